// Round 1
// baseline (149.846 us; speedup 1.0000x reference)
//
#include <hip/hip_runtime.h>

// Poincare contrastive loss, N=4096, D=8, TEMP=0.5.
// z = concat(z_i, z_j) [2N, D]; sim[i][j] = 1/(1+arcosh(x_ij));
// loss = mean_i -(2*sim[i,partner(i)] - log(sum_{j!=i} exp(2*sim[i][j])))

#define D 8
constexpr int BLOCK = 256;   // threads per block, 1 row per thread
constexpr int JC    = 256;   // j-chunk staged in LDS per block
#define TEMP_INV 2.0f        // 1/TEMP
#define BOUNDARY (1.0f - 1e-5f)

__device__ __forceinline__ float fast_rcp(float x)  { return __builtin_amdgcn_rcpf(x); }
__device__ __forceinline__ float fast_sqrt(float x) { return __builtin_amdgcn_sqrtf(x); }

__global__ __launch_bounds__(BLOCK) void poincare_pair_kernel(
    const float* __restrict__ zi, const float* __restrict__ zj,
    float* __restrict__ denom, float* __restrict__ pos, int N)
{
    __shared__ float  s_z[JC][D];     // 8 KB
    __shared__ float2 s_ri[JC];       // raw, 1/(1-sqc)  (2 KB)

    const int tid   = threadIdx.x;
    const int row   = blockIdx.x * BLOCK + tid;
    const int jbase = blockIdx.y * JC;

    // ---- stage chunk rows [jbase, jbase+JC) as flat float4 loads ----
    for (int f = tid; f < JC * D / 4; f += BLOCK) {
        int r = jbase + (f >> 1);          // 2 float4 per row
        int h = f & 1;
        const float* src = (r < N) ? (zi + (size_t)r * D)
                                   : (zj + (size_t)(r - N) * D);
        float4 v = *(const float4*)(src + h * 4);
        *(float4*)(&s_z[f >> 1][h * 4]) = v;
    }
    __syncthreads();

    // ---- per chunk-row raw norm + 1/(1-sqc) ----
    for (int r = tid; r < JC; r += BLOCK) {
        float raw = 0.f;
        #pragma unroll
        for (int d = 0; d < D; ++d) raw += s_z[r][d] * s_z[r][d];
        float sqc = fminf(raw, BOUNDARY);
        s_ri[r] = make_float2(raw, fast_rcp(1.0f - sqc));
    }
    __syncthreads();

    // ---- own row into registers ----
    const float* srcI = (row < N) ? (zi + (size_t)row * D)
                                  : (zj + (size_t)(row - N) * D);
    float z[D];
    #pragma unroll
    for (int d = 0; d < D; ++d) z[d] = srcI[d];
    float raw_i = 0.f;
    #pragma unroll
    for (int d = 0; d < D; ++d) raw_i += z[d] * z[d];
    float sqc_i  = fminf(raw_i, BOUNDARY);
    float inv2_i = 2.0f * fast_rcp(1.0f - sqc_i);

    const int partner = (row < N) ? (row + N) : (row - N);

    float dsum = 0.f;
    float psim = 0.f;

    #pragma unroll 4
    for (int jj = 0; jj < JC; ++jj) {
        // wave-uniform LDS broadcast reads (conflict-free)
        float4 a  = *(const float4*)&s_z[jj][0];
        float4 b  = *(const float4*)&s_z[jj][4];
        float2 ri = s_ri[jj];

        float dot = z[0]*a.x + z[1]*a.y + z[2]*a.z + z[3]*a.w
                  + z[4]*b.x + z[5]*b.y + z[6]*b.z + z[7]*b.w;
        float sqdist = fmaxf(raw_i + ri.x - 2.0f * dot, 0.0f);
        float x   = fmaf(sqdist, inv2_i * ri.y, 1.0f);   // 2*sqdist*inv_i*inv_j + 1
        float t   = fmaf(x, x, -1.0f);
        float s   = fast_sqrt(fmaxf(t, 0.0f));           // safe_sqrt
        float dist = __logf(x + s);                      // arcosh(x)
        float sim  = fast_rcp(1.0f + dist);
        float e    = __expf(TEMP_INV * sim);

        int j = jbase + jj;
        dsum += (j == row) ? 0.0f : e;                   // exclude self
        psim  = (j == partner) ? sim : psim;             // capture positive
    }

    atomicAdd(&denom[row], dsum);
    if (partner >= jbase && partner < jbase + JC) pos[row] = psim;
}

__global__ __launch_bounds__(256) void poincare_reduce_kernel(
    const float* __restrict__ denom, const float* __restrict__ pos,
    float* __restrict__ out, int twoN)
{
    __shared__ float s_red[256];
    const int tid = threadIdx.x;
    float acc = 0.f;
    for (int i = tid; i < twoN; i += 256) {
        acc += -(pos[i] * TEMP_INV - __logf(denom[i]));
    }
    s_red[tid] = acc;
    __syncthreads();
    for (int off = 128; off > 0; off >>= 1) {
        if (tid < off) s_red[tid] += s_red[tid + off];
        __syncthreads();
    }
    if (tid == 0) out[0] = s_red[0] / (float)twoN;
}

extern "C" void kernel_launch(void* const* d_in, const int* in_sizes, int n_in,
                              void* d_out, int out_size, void* d_ws, size_t ws_size,
                              hipStream_t stream) {
    const float* zi = (const float*)d_in[0];
    const float* zj = (const float*)d_in[1];
    const int N    = in_sizes[0] / D;   // 4096
    const int twoN = 2 * N;             // 8192

    float* denom = (float*)d_ws;
    float* pos   = denom + twoN;

    // ws is re-poisoned to 0xAA before every call — zero what we accumulate into
    hipMemsetAsync(d_ws, 0, (size_t)twoN * 2 * sizeof(float), stream);

    dim3 grid(twoN / BLOCK, twoN / JC);   // 32 x 32 = 1024 blocks
    poincare_pair_kernel<<<grid, BLOCK, 0, stream>>>(zi, zj, denom, pos, N);
    poincare_reduce_kernel<<<1, 256, 0, stream>>>(denom, pos, (float*)d_out, twoN);
}

// Round 2
// 113.746 us; speedup vs baseline: 1.3174x; 1.3174x over previous
//
#include <hip/hip_runtime.h>

// Poincare contrastive loss, N=4096, D=8, TEMP=0.5.
// sim[i][j] = 1/(1+arcosh(x_ij)), x_ij = 1 + 2*sqdist/((1-sqc_i)(1-sqc_j))
// Rewrite: x = 1 + P_i . Q_j  (10-term dot)
//   Q_j = [z_j(8), inv_j, inv_j*raw_j],  inv = 1/(1-min(raw,BOUNDARY))
//   P_i = [-4*inv_i*z_i(8), 2*inv_i*raw_i, 2*inv_i]
// loss = mean_i -(2*sim[i,partner] - log(sum_{j!=i} exp(2*sim[i][j])))
// Self term included in the sum, exp(2) subtracted in the epilogue.

#define D 8
#define QS 12                // padded Q stride (floats) -> 48B, 16B-aligned
#define TWO_N 8192
#define HALF_N 4096
constexpr int BLOCK = 256;
constexpr int R     = 4;     // rows per thread
constexpr int JC    = 32;    // j-chunk staged in LDS per block
#define BOUNDARY (1.0f - 1e-5f)
#define LN2 0.6931471805599453f
#define TWO_LOG2E 2.8853900817779268f   // 2*log2(e)
#define E2 7.38905609893065f            // exp(2): self term

__device__ __forceinline__ float frcp(float x)  { return __builtin_amdgcn_rcpf(x); }
__device__ __forceinline__ float fsqrt(float x) { return __builtin_amdgcn_sqrtf(x); }
__device__ __forceinline__ float flog2(float x) { return __builtin_amdgcn_logf(x); }
__device__ __forceinline__ float fexp2(float x) { return __builtin_amdgcn_exp2f(x); }

// ---- build Q[row] = [z(8), inv, inv*raw, 0, 0] ----
__global__ __launch_bounds__(256) void prep_kernel(
    const float* __restrict__ zi, const float* __restrict__ zj,
    float* __restrict__ q)
{
    const int row = blockIdx.x * 256 + threadIdx.x;        // grid 32 x 256
    const float* src = (row < HALF_N) ? (zi + (size_t)row * D)
                                      : (zj + (size_t)(row - HALF_N) * D);
    float4 a = *(const float4*)(src);
    float4 b = *(const float4*)(src + 4);
    float raw = a.x*a.x + a.y*a.y + a.z*a.z + a.w*a.w
              + b.x*b.x + b.y*b.y + b.z*b.z + b.w*b.w;     // unclamped
    float inv = frcp(1.0f - fminf(raw, BOUNDARY));
    float* dst = q + (size_t)row * QS;
    *(float4*)(dst)     = a;
    *(float4*)(dst + 4) = b;
    *(float4*)(dst + 8) = make_float4(inv, inv * raw, 0.0f, 0.0f);
}

// ---- pair kernel: denom[i] += sum_j exp(2*sim(i,j)) over a JC chunk ----
__global__ __launch_bounds__(BLOCK, 6) void pair_kernel(
    const float* __restrict__ q, float* __restrict__ denom)
{
    __shared__ float sq[JC * QS];       // 1.5 KB

    const int tid   = threadIdx.x;
    const int ibase = blockIdx.x * (BLOCK * R);   // 8 i-blocks of 1024 rows
    const int jbase = blockIdx.y * JC;            // 256 j-chunks of 32

    // stage j-chunk: JC*QS/4 = 96 float4
    if (tid < JC * QS / 4)
        ((float4*)sq)[tid] = ((const float4*)(q + (size_t)jbase * QS))[tid];

    // load own rows, build P in registers
    float p[R][10];
    float acc[R];
    #pragma unroll
    for (int r = 0; r < R; ++r) {
        const int row = ibase + tid + r * BLOCK;
        const float* qr = q + (size_t)row * QS;
        float4 a = *(const float4*)(qr);
        float4 b = *(const float4*)(qr + 4);
        float4 c = *(const float4*)(qr + 8);      // c.x=inv, c.y=inv*raw
        const float m = -4.0f * c.x;
        p[r][0] = m * a.x; p[r][1] = m * a.y; p[r][2] = m * a.z; p[r][3] = m * a.w;
        p[r][4] = m * b.x; p[r][5] = m * b.y; p[r][6] = m * b.z; p[r][7] = m * b.w;
        p[r][8] = 2.0f * c.y;                     // pairs with inv_j
        p[r][9] = 2.0f * c.x;                     // pairs with inv_j*raw_j
        acc[r] = 0.0f;
    }
    __syncthreads();

    #pragma unroll 2
    for (int jj = 0; jj < JC; ++jj) {
        const float* qq = sq + jj * QS;
        float4 a = *(const float4*)(qq);          // broadcast, 16B-aligned
        float4 b = *(const float4*)(qq + 4);
        float2 c = *(const float2*)(qq + 8);      // inv_j, inv_j*raw_j
        #pragma unroll
        for (int r = 0; r < R; ++r) {
            float x = 1.0f;
            x = fmaf(p[r][0], a.x, x); x = fmaf(p[r][1], a.y, x);
            x = fmaf(p[r][2], a.z, x); x = fmaf(p[r][3], a.w, x);
            x = fmaf(p[r][4], b.x, x); x = fmaf(p[r][5], b.y, x);
            x = fmaf(p[r][6], b.z, x); x = fmaf(p[r][7], b.w, x);
            x = fmaf(p[r][8], c.x, x); x = fmaf(p[r][9], c.y, x);
            float t = fmaf(x, x, -1.0f);
            float s = fsqrt(fmaxf(t, 0.0f));
            float l = flog2(x + s);               // log2(arcosh arg)
            float dd = fmaf(l, LN2, 1.0f);        // 1 + dist
            float sim = frcp(dd);
            float e = fexp2(sim * TWO_LOG2E);     // exp(2*sim)
            acc[r] += e;
        }
    }

    #pragma unroll
    for (int r = 0; r < R; ++r)
        atomicAdd(&denom[ibase + tid + r * BLOCK], acc[r]);
}

// ---- epilogue: positives computed exactly, subtract self term, reduce ----
__global__ __launch_bounds__(256) void reduce_kernel(
    const float* __restrict__ zi, const float* __restrict__ zj,
    const float* __restrict__ denom, float* __restrict__ out)
{
    __shared__ float s_red[256];
    const int tid = threadIdx.x;
    float acc = 0.0f;
    for (int i = tid; i < TWO_N; i += 256) {
        const int base = (i < HALF_N) ? i : (i - HALF_N);
        const float* pa = (i < HALF_N) ? (zi + (size_t)base * D) : (zj + (size_t)base * D);
        const float* pb = (i < HALF_N) ? (zj + (size_t)base * D) : (zi + (size_t)base * D);
        float4 a0 = *(const float4*)(pa), a1 = *(const float4*)(pa + 4);
        float4 b0 = *(const float4*)(pb), b1 = *(const float4*)(pb + 4);
        float rawa = a0.x*a0.x + a0.y*a0.y + a0.z*a0.z + a0.w*a0.w
                   + a1.x*a1.x + a1.y*a1.y + a1.z*a1.z + a1.w*a1.w;
        float rawb = b0.x*b0.x + b0.y*b0.y + b0.z*b0.z + b0.w*b0.w
                   + b1.x*b1.x + b1.y*b1.y + b1.z*b1.z + b1.w*b1.w;
        float dot  = a0.x*b0.x + a0.y*b0.y + a0.z*b0.z + a0.w*b0.w
                   + a1.x*b1.x + a1.y*b1.y + a1.z*b1.z + a1.w*b1.w;
        float sqd  = fmaxf(rawa + rawb - 2.0f * dot, 0.0f);
        float inva = frcp(1.0f - fminf(rawa, BOUNDARY));
        float invb = frcp(1.0f - fminf(rawb, BOUNDARY));
        float x    = fmaf(2.0f * sqd, inva * invb, 1.0f);
        float t    = fmaf(x, x, -1.0f);
        float s    = fsqrt(fmaxf(t, 0.0f));
        float dist = flog2(x + s) * LN2;
        float sim  = frcp(1.0f + dist);           // positive pair similarity
        float dlog = flog2(denom[i] - E2) * LN2;  // ln(denom excl. self)
        acc += -(2.0f * sim - dlog);
    }
    s_red[tid] = acc;
    __syncthreads();
    for (int off = 128; off > 0; off >>= 1) {
        if (tid < off) s_red[tid] += s_red[tid + off];
        __syncthreads();
    }
    if (tid == 0) out[0] = s_red[0] / (float)TWO_N;
}

extern "C" void kernel_launch(void* const* d_in, const int* in_sizes, int n_in,
                              void* d_out, int out_size, void* d_ws, size_t ws_size,
                              hipStream_t stream) {
    const float* zi = (const float*)d_in[0];
    const float* zj = (const float*)d_in[1];

    float* denom = (float*)d_ws;                  // [8192]
    float* q     = denom + TWO_N;                 // [8192 * 12]

    hipMemsetAsync(denom, 0, (size_t)TWO_N * sizeof(float), stream);

    prep_kernel<<<TWO_N / 256, 256, 0, stream>>>(zi, zj, q);

    dim3 grid(TWO_N / (BLOCK * R), TWO_N / JC);   // 8 x 256 = 2048 blocks
    pair_kernel<<<grid, BLOCK, 0, stream>>>(q, denom);

    reduce_kernel<<<1, 256, 0, stream>>>(zi, zj, denom, (float*)d_out);
}

// Round 3
// 100.826 us; speedup vs baseline: 1.4862x; 1.1281x over previous
//
#include <hip/hip_runtime.h>

// Poincare contrastive loss, N=4096, D=8, TEMP=0.5.
// sim[i][j] = 1/(1+arcosh(x_ij)), x_ij = 1 + 2*sqdist/((1-sqc_i)(1-sqc_j))
// Rewrite: x = 1 + P_i . Q_j  (10-term dot)
//   Q_j = [z_j(8), inv_j, inv_j*raw_j],  inv = 1/(1-min(raw,BOUNDARY))
//   P_i = [-4*inv_i*z_i(8), 2*inv_i*raw_i, 2*inv_i]
// loss = mean_i -(2*sim[i,partner] - log(sum_{j!=i} exp(2*sim[i][j])))
// Self term included in the sum, exp(2) subtracted in the epilogue.

#define D 8
#define QS 12                // padded Q stride (floats) -> 48B, 16B-aligned
#define TWO_N 8192
#define HALF_N 4096
constexpr int BLOCK = 256;
constexpr int R     = 4;     // rows per thread
constexpr int JC    = 32;    // j-chunk staged in LDS per block
#define BOUNDARY (1.0f - 1e-5f)
#define LN2 0.6931471805599453f
#define TWO_LOG2E 2.8853900817779268f   // 2*log2(e)
#define E2 7.38905609893065f            // exp(2): self term

__device__ __forceinline__ float frcp(float x)  { return __builtin_amdgcn_rcpf(x); }
__device__ __forceinline__ float fsqrt(float x) { return __builtin_amdgcn_sqrtf(x); }
__device__ __forceinline__ float flog2(float x) { return __builtin_amdgcn_logf(x); }
__device__ __forceinline__ float fexp2(float x) { return __builtin_amdgcn_exp2f(x); }

// ---- build Q[row] = [z(8), inv, inv*raw, 0, 0] ----
__global__ __launch_bounds__(256) void prep_kernel(
    const float* __restrict__ zi, const float* __restrict__ zj,
    float* __restrict__ q)
{
    const int row = blockIdx.x * 256 + threadIdx.x;        // grid 32 x 256
    const float* src = (row < HALF_N) ? (zi + (size_t)row * D)
                                      : (zj + (size_t)(row - HALF_N) * D);
    float4 a = *(const float4*)(src);
    float4 b = *(const float4*)(src + 4);
    float raw = a.x*a.x + a.y*a.y + a.z*a.z + a.w*a.w
              + b.x*b.x + b.y*b.y + b.z*b.z + b.w*b.w;     // unclamped
    float inv = frcp(1.0f - fminf(raw, BOUNDARY));
    float* dst = q + (size_t)row * QS;
    *(float4*)(dst)     = a;
    *(float4*)(dst + 4) = b;
    *(float4*)(dst + 8) = make_float4(inv, inv * raw, 0.0f, 0.0f);
}

// ---- pair kernel: denom[i] += sum_j exp(2*sim(i,j)) over a JC chunk ----
__global__ __launch_bounds__(BLOCK, 6) void pair_kernel(
    const float* __restrict__ q, float* __restrict__ denom)
{
    __shared__ float sq[JC * QS];       // 1.5 KB

    const int tid   = threadIdx.x;
    const int ibase = blockIdx.x * (BLOCK * R);   // 8 i-blocks of 1024 rows
    const int jbase = blockIdx.y * JC;            // 256 j-chunks of 32

    // stage j-chunk: JC*QS/4 = 96 float4
    if (tid < JC * QS / 4)
        ((float4*)sq)[tid] = ((const float4*)(q + (size_t)jbase * QS))[tid];

    // load own rows, build P in registers
    float p[R][10];
    float acc[R];
    #pragma unroll
    for (int r = 0; r < R; ++r) {
        const int row = ibase + tid + r * BLOCK;
        const float* qr = q + (size_t)row * QS;
        float4 a = *(const float4*)(qr);
        float4 b = *(const float4*)(qr + 4);
        float4 c = *(const float4*)(qr + 8);      // c.x=inv, c.y=inv*raw
        const float m = -4.0f * c.x;
        p[r][0] = m * a.x; p[r][1] = m * a.y; p[r][2] = m * a.z; p[r][3] = m * a.w;
        p[r][4] = m * b.x; p[r][5] = m * b.y; p[r][6] = m * b.z; p[r][7] = m * b.w;
        p[r][8] = 2.0f * c.y;                     // pairs with inv_j
        p[r][9] = 2.0f * c.x;                     // pairs with inv_j*raw_j
        acc[r] = 0.0f;
    }
    __syncthreads();

    #pragma unroll 2
    for (int jj = 0; jj < JC; ++jj) {
        const float* qq = sq + jj * QS;
        float4 a = *(const float4*)(qq);          // broadcast, 16B-aligned
        float4 b = *(const float4*)(qq + 4);
        float2 c = *(const float2*)(qq + 8);      // inv_j, inv_j*raw_j
        #pragma unroll
        for (int r = 0; r < R; ++r) {
            float x = 1.0f;
            x = fmaf(p[r][0], a.x, x); x = fmaf(p[r][1], a.y, x);
            x = fmaf(p[r][2], a.z, x); x = fmaf(p[r][3], a.w, x);
            x = fmaf(p[r][4], b.x, x); x = fmaf(p[r][5], b.y, x);
            x = fmaf(p[r][6], b.z, x); x = fmaf(p[r][7], b.w, x);
            x = fmaf(p[r][8], c.x, x); x = fmaf(p[r][9], c.y, x);
            float t = fmaf(x, x, -1.0f);
            float s = fsqrt(fmaxf(t, 0.0f));
            float l = flog2(x + s);               // log2(arcosh arg)
            float dd = fmaf(l, LN2, 1.0f);        // 1 + dist
            float sim = frcp(dd);
            float e = fexp2(sim * TWO_LOG2E);     // exp(2*sim)
            acc[r] += e;
        }
    }

    #pragma unroll
    for (int r = 0; r < R; ++r)
        atomicAdd(&denom[ibase + tid + r * BLOCK], acc[r]);
}

// ---- epilogue: positives exact, subtract self term, parallel reduce ----
// 32 blocks x 256 threads: one i per thread, block-reduce, one atomic per block.
__global__ __launch_bounds__(256) void reduce_kernel(
    const float* __restrict__ zi, const float* __restrict__ zj,
    const float* __restrict__ denom, float* __restrict__ out)
{
    __shared__ float s_red[256];
    const int tid = threadIdx.x;
    const int i   = blockIdx.x * 256 + tid;       // grid 32 -> covers 8192

    const int base = (i < HALF_N) ? i : (i - HALF_N);
    const float* pa = (i < HALF_N) ? (zi + (size_t)base * D) : (zj + (size_t)base * D);
    const float* pb = (i < HALF_N) ? (zj + (size_t)base * D) : (zi + (size_t)base * D);
    float4 a0 = *(const float4*)(pa), a1 = *(const float4*)(pa + 4);
    float4 b0 = *(const float4*)(pb), b1 = *(const float4*)(pb + 4);
    float rawa = a0.x*a0.x + a0.y*a0.y + a0.z*a0.z + a0.w*a0.w
               + a1.x*a1.x + a1.y*a1.y + a1.z*a1.z + a1.w*a1.w;
    float rawb = b0.x*b0.x + b0.y*b0.y + b0.z*b0.z + b0.w*b0.w
               + b1.x*b1.x + b1.y*b1.y + b1.z*b1.z + b1.w*b1.w;
    float dot  = a0.x*b0.x + a0.y*b0.y + a0.z*b0.z + a0.w*b0.w
               + a1.x*b1.x + a1.y*b1.y + a1.z*b1.z + a1.w*b1.w;
    float sqd  = fmaxf(rawa + rawb - 2.0f * dot, 0.0f);
    float inva = frcp(1.0f - fminf(rawa, BOUNDARY));
    float invb = frcp(1.0f - fminf(rawb, BOUNDARY));
    float x    = fmaf(2.0f * sqd, inva * invb, 1.0f);
    float t    = fmaf(x, x, -1.0f);
    float s    = fsqrt(fmaxf(t, 0.0f));
    float dist = flog2(x + s) * LN2;
    float sim  = frcp(1.0f + dist);               // positive pair similarity
    float dlog = flog2(denom[i] - E2) * LN2;      // ln(denom excl. self)
    float term = -(2.0f * sim - dlog);

    s_red[tid] = term;
    __syncthreads();
    for (int off = 128; off > 0; off >>= 1) {
        if (tid < off) s_red[tid] += s_red[tid + off];
        __syncthreads();
    }
    if (tid == 0) atomicAdd(out, s_red[0] * (1.0f / (float)TWO_N));
}

extern "C" void kernel_launch(void* const* d_in, const int* in_sizes, int n_in,
                              void* d_out, int out_size, void* d_ws, size_t ws_size,
                              hipStream_t stream) {
    const float* zi = (const float*)d_in[0];
    const float* zj = (const float*)d_in[1];

    float* denom = (float*)d_ws;                  // [8192]
    float* q     = denom + TWO_N;                 // [8192 * 12]

    hipMemsetAsync(denom, 0, (size_t)TWO_N * sizeof(float), stream);
    hipMemsetAsync(d_out, 0, sizeof(float), stream);   // accumulated via atomics

    prep_kernel<<<TWO_N / 256, 256, 0, stream>>>(zi, zj, q);

    dim3 grid(TWO_N / (BLOCK * R), TWO_N / JC);   // 8 x 256 = 2048 blocks
    pair_kernel<<<grid, BLOCK, 0, stream>>>(q, denom);

    reduce_kernel<<<TWO_N / 256, 256, 0, stream>>>(zi, zj, denom, (float*)d_out);
}